// Round 1
// baseline (626.135 us; speedup 1.0000x reference)
//
#include <hip/hip_runtime.h>
#include <math.h>

#define NN 10000
#define NE 160000

constexpr float SQRT3f    = 1.7320508075688772f;
constexpr float ISQRT3    = 0.57735026918962576f;
constexpr float ISQRT32   = 0.17677669529663687f;   // 1/sqrt(32)
constexpr float C_TP      = 0.14433756729740645f;   // 1/sqrt(48)
constexpr float CSIM      = 0.11180339887498949f;   // 1/sqrt(80)
constexpr float PREB      = 5.0596442562694074f;    // sqrt(2/2.5)*sqrt(32)
constexpr float PI_OVER_R = 1.2566370614359172f;    // pi/2.5
constexpr float INV_RMAX  = 0.4f;                   // 1/2.5

// ---- float <-> order-preserving unsigned key (for atomicMax on floats) ----
__device__ __forceinline__ unsigned fkey(float f) {
  unsigned u = __float_as_uint(f);
  return (u & 0x80000000u) ? ~u : (u | 0x80000000u);
}
__device__ __forceinline__ float funkey(unsigned k) {
  return (k & 0x80000000u) ? __uint_as_float(k ^ 0x80000000u)
                           : __uint_as_float(~k);
}

// ---- shared per-edge prologue: geometry + bessel basis + feature load ----
__device__ __forceinline__ void edge_prologue(
    const float* __restrict__ x, const float* __restrict__ pos,
    int s, int d,
    float rb[32], float x0[32], float x1f[48], float xdYs[16],
    float& Yx, float& Yy, float& Yz, float& r)
{
  float vx = pos[3 * s + 0] - pos[3 * d + 0];
  float vy = pos[3 * s + 1] - pos[3 * d + 1];
  float vz = pos[3 * s + 2] - pos[3 * d + 2];
  r = sqrtf(fmaf(vx, vx, fmaf(vy, vy, vz * vz)) + 1e-24f);
  float inv_r = 1.0f / r;

  // rb[n] = sqrt(2/2.5)*sqrt(32) * sin((n+1)*pi*r/2.5) / r via sin recurrence
  float sn, cth;
  sincosf(PI_OVER_R * r, &sn, &cth);
  float twoc = 2.0f * cth;
  float pre = PREB * inv_r;
  float snm1 = 0.0f;
#pragma unroll
  for (int n = 0; n < 32; ++n) {
    rb[n] = pre * sn;
    float t = fmaf(twoc, sn, -snm1);
    snm1 = sn; sn = t;
  }

  Yx = SQRT3f * vx * inv_r;
  Yy = SQRT3f * vy * inv_r;
  Yz = SQRT3f * vz * inv_r;

  const float4* xr = reinterpret_cast<const float4*>(x + 80 * s);
#pragma unroll
  for (int i = 0; i < 8; ++i) {
    float4 v = xr[i];
    x0[4 * i + 0] = v.x; x0[4 * i + 1] = v.y;
    x0[4 * i + 2] = v.z; x0[4 * i + 3] = v.w;
  }
#pragma unroll
  for (int i = 0; i < 12; ++i) {
    float4 v = xr[8 + i];
    x1f[4 * i + 0] = v.x; x1f[4 * i + 1] = v.y;
    x1f[4 * i + 2] = v.z; x1f[4 * i + 3] = v.w;
  }
#pragma unroll
  for (int u = 0; u < 16; ++u)
    xdYs[u] = ISQRT3 * fmaf(x1f[3 * u], Yx,
                       fmaf(x1f[3 * u + 1], Yy, x1f[3 * u + 2] * Yz));
}

// ---- basis-net (2nd layer) fused with the tensor-product contraction ----
// out0[w]   = Sum_h hhs * ( W2[h, u*8+w]*x0[u] + W2[h,256+u*8+w]*xdYs[u] )
// s01[w]    = Sum_h hhs * W2[h,384+u*4+w]*x0[u]      (caller adds s01[w]*Y[m])
// out1[w][m]= Sum_h hhs * W2[h,512+u*4+w]*x1[u][m]
// hhs = silu((rb@W1)[h]/sqrt(32)) * (1/sqrt(48)) * (1/sqrt(32))
__device__ __forceinline__ void tp_net(
    const float rb[32], const float x0[32], const float x1f[48],
    const float xdYs[16],
    const float* __restrict__ w1, const float* __restrict__ w2,
    float out0[8], float s01[4], float out1[4][3])
{
#pragma unroll
  for (int w = 0; w < 8; ++w) out0[w] = 0.0f;
#pragma unroll
  for (int w = 0; w < 4; ++w) {
    s01[w] = 0.0f;
    out1[w][0] = 0.0f; out1[w][1] = 0.0f; out1[w][2] = 0.0f;
  }
#pragma unroll 1
  for (int h = 0; h < 32; ++h) {
    float acc = 0.0f;
#pragma unroll
    for (int n = 0; n < 32; ++n) acc = fmaf(rb[n], w1[n * 32 + h], acc);
    acc *= ISQRT32;
    float hh = acc / (1.0f + __expf(-acc));      // silu
    float hhs = hh * (C_TP * ISQRT32);
    const float* W = w2 + h * 576;
#pragma unroll
    for (int u = 0; u < 32; ++u) {
      float t = hhs * x0[u];
#pragma unroll
      for (int w = 0; w < 8; ++w) out0[w] = fmaf(t, W[u * 8 + w], out0[w]);
#pragma unroll
      for (int w = 0; w < 4; ++w) s01[w] = fmaf(t, W[384 + u * 4 + w], s01[w]);
    }
#pragma unroll
    for (int u = 0; u < 16; ++u) {
      float t = hhs * xdYs[u];
#pragma unroll
      for (int w = 0; w < 8; ++w) out0[w] = fmaf(t, W[256 + u * 8 + w], out0[w]);
    }
#pragma unroll
    for (int u = 0; u < 16; ++u) {
#pragma unroll
      for (int w = 0; w < 4; ++w) {
        float t = hhs * W[512 + u * 4 + w];
        out1[w][0] = fmaf(t, x1f[3 * u + 0], out1[w][0]);
        out1[w][1] = fmaf(t, x1f[3 * u + 1], out1[w][1]);
        out1[w][2] = fmaf(t, x1f[3 * u + 2], out1[w][2]);
      }
    }
  }
}

// ---- E1: logits per edge (k-net + query + similarity + cutoff) ----
__global__ void __launch_bounds__(256) k_edge_logits(
    const float* __restrict__ x, const float* __restrict__ pos,
    const float* __restrict__ w_q0, const float* __restrict__ w_q1,
    const float* __restrict__ w_kb1, const float* __restrict__ w_kb2,
    const float* __restrict__ w_sim0, const float* __restrict__ w_sim1,
    const int* __restrict__ esrc, const int* __restrict__ edst,
    float* __restrict__ logits, unsigned* __restrict__ mkey)
{
  int e = blockIdx.x * 256 + threadIdx.x;
  if (e >= NE) return;
  int s = esrc[e], d = edst[e];

  float rb[32], x0[32], x1f[48], xdYs[16], Yx, Yy, Yz, r;
  edge_prologue(x, pos, s, d, rb, x0, x1f, xdYs, Yx, Yy, Yz, r);

  float k0[8], s01[4], k1[4][3];
  tp_net(rb, x0, x1f, xdYs, w_kb1, w_kb2, k0, s01, k1);
#pragma unroll
  for (int w = 0; w < 4; ++w) {
    k1[w][0] = fmaf(s01[w], Yx, k1[w][0]);
    k1[w][1] = fmaf(s01[w], Yy, k1[w][1]);
    k1[w][2] = fmaf(s01[w], Yz, k1[w][2]);
  }

  // query projection for node s
  float q0[8];
#pragma unroll
  for (int w = 0; w < 8; ++w) {
    float a = 0.0f;
#pragma unroll
    for (int u = 0; u < 32; ++u) a = fmaf(x0[u], w_q0[u * 8 + w], a);
    q0[w] = a * ISQRT32;
  }
  float q1[4][3];
#pragma unroll
  for (int w = 0; w < 4; ++w) {
#pragma unroll
    for (int m = 0; m < 3; ++m) {
      float a = 0.0f;
#pragma unroll
      for (int u = 0; u < 16; ++u) a = fmaf(x1f[3 * u + m], w_q1[u * 4 + w], a);
      q1[w][m] = a * 0.25f;
    }
  }

  float sim0 = 0.0f;
#pragma unroll
  for (int u = 0; u < 8; ++u) {
#pragma unroll
    for (int v = 0; v < 8; ++v)
      sim0 = fmaf(w_sim0[u * 8 + v] * q0[u], k0[v], sim0);
  }
  float sim1 = 0.0f;
#pragma unroll
  for (int u = 0; u < 4; ++u) {
#pragma unroll
    for (int v = 0; v < 4; ++v) {
      float dt = fmaf(q1[u][0], k1[v][0],
                 fmaf(q1[u][1], k1[v][1], q1[u][2] * k1[v][2]));
      sim1 = fmaf(w_sim1[u * 4 + v], dt, sim1);
    }
  }
  float sim = CSIM * fmaf(sim1, ISQRT3, sim0);

  float tc = 10.0f * (1.0f - r * INV_RMAX);
  float cut = (tc > 0.0f) ? __expf(-1.0f / tc) : 0.0f;

  float lg = cut * sim;
  logits[e] = lg;
  atomicMax(&mkey[s], fkey(lg));
}

// ---- E2: values per edge (v-net) ----
__global__ void __launch_bounds__(256) k_edge_vals(
    const float* __restrict__ x, const float* __restrict__ pos,
    const float* __restrict__ w_vb1, const float* __restrict__ w_vb2,
    const int* __restrict__ esrc, const int* __restrict__ edst,
    float* __restrict__ vals)
{
  int e = blockIdx.x * 256 + threadIdx.x;
  if (e >= NE) return;
  int s = esrc[e], d = edst[e];

  float rb[32], x0[32], x1f[48], xdYs[16], Yx, Yy, Yz, r;
  edge_prologue(x, pos, s, d, rb, x0, x1f, xdYs, Yx, Yy, Yz, r);

  float v0[8], s01[4], v1[4][3];
  tp_net(rb, x0, x1f, xdYs, w_vb1, w_vb2, v0, s01, v1);
#pragma unroll
  for (int w = 0; w < 4; ++w) {
    v1[w][0] = fmaf(s01[w], Yx, v1[w][0]);
    v1[w][1] = fmaf(s01[w], Yy, v1[w][1]);
    v1[w][2] = fmaf(s01[w], Yz, v1[w][2]);
  }
  float* o = vals + 20 * e;
#pragma unroll
  for (int w = 0; w < 8; ++w) o[w] = v0[w];
#pragma unroll
  for (int w = 0; w < 4; ++w) {
    o[8 + 3 * w + 0] = v1[w][0];
    o[8 + 3 * w + 1] = v1[w][1];
    o[8 + 3 * w + 2] = v1[w][2];
  }
}

// ---- S3: exp(logit - max) and denominator accumulation ----
__global__ void __launch_bounds__(256) k_softmax_den(
    const float* __restrict__ logits, const int* __restrict__ esrc,
    const unsigned* __restrict__ mkey,
    float* __restrict__ exb, float* __restrict__ den)
{
  int e = blockIdx.x * 256 + threadIdx.x;
  if (e >= NE) return;
  int s = esrc[e];
  float m = funkey(mkey[s]);
  float ex = expf(logits[e] - m);
  exb[e] = ex;
  atomicAdd(&den[s], ex);
}

// ---- S4: normalize, sqrt, scatter to output ----
__global__ void __launch_bounds__(256) k_scatter(
    const float* __restrict__ exb, const float* __restrict__ den,
    const float* __restrict__ vals, const int* __restrict__ esrc,
    const int* __restrict__ edst, float* __restrict__ out)
{
  int idx = blockIdx.x * 256 + threadIdx.x;
  if (idx >= NE * 20) return;
  int e = idx / 20;
  int j = idx - 20 * e;
  float attn = exb[e] / den[esrc[e]];
  float a = sqrtf(fmaxf(attn, 0.0f)) * (1.0f / 32.0f);  // sqrt(relu)/NUM_NEIGHBORS
  atomicAdd(&out[20 * edst[e] + j], a * vals[idx]);
}

extern "C" void kernel_launch(void* const* d_in, const int* in_sizes, int n_in,
                              void* d_out, int out_size, void* d_ws, size_t ws_size,
                              hipStream_t stream)
{
  const float* x      = (const float*)d_in[0];
  const float* pos    = (const float*)d_in[1];
  const float* w_q0   = (const float*)d_in[2];
  const float* w_q1   = (const float*)d_in[3];
  const float* w_kb1  = (const float*)d_in[4];
  const float* w_kb2  = (const float*)d_in[5];
  const float* w_vb1  = (const float*)d_in[6];
  const float* w_vb2  = (const float*)d_in[7];
  const float* w_sim0 = (const float*)d_in[8];
  const float* w_sim1 = (const float*)d_in[9];
  const int*   eidx   = (const int*)d_in[10];
  const int* esrc = eidx;
  const int* edst = eidx + NE;
  float* out = (float*)d_out;

  // workspace layout (floats): vals[NE*20] | logits[NE] | exb[NE] | den[NN] | mkey[NN]
  float* ws      = (float*)d_ws;
  float* vals    = ws;
  float* logits  = vals + (size_t)NE * 20;
  float* exb     = logits + NE;
  float* den     = exb + NE;
  unsigned* mkey = (unsigned*)(den + NN);

  hipMemsetAsync(d_out, 0, (size_t)NN * 20 * sizeof(float), stream);
  hipMemsetAsync(den, 0, (size_t)NN * 2 * sizeof(float), stream);  // den + mkey

  const int eb = (NE + 255) / 256;
  k_edge_logits<<<dim3(eb), dim3(256), 0, stream>>>(
      x, pos, w_q0, w_q1, w_kb1, w_kb2, w_sim0, w_sim1, esrc, edst, logits, mkey);
  k_edge_vals<<<dim3(eb), dim3(256), 0, stream>>>(
      x, pos, w_vb1, w_vb2, esrc, edst, vals);
  k_softmax_den<<<dim3(eb), dim3(256), 0, stream>>>(logits, esrc, mkey, exb, den);
  k_scatter<<<dim3((NE * 20 + 255) / 256), dim3(256), 0, stream>>>(
      exb, den, vals, esrc, edst, out);
}

// Round 2
// 262.315 us; speedup vs baseline: 2.3870x; 2.3870x over previous
//
#include <hip/hip_runtime.h>
#include <math.h>

#define NN 10000
#define NE 160000

typedef __attribute__((ext_vector_type(8))) short short8;
typedef __attribute__((ext_vector_type(4))) float f32x4;

constexpr float SQRT3f    = 1.7320508075688772f;
constexpr float ISQRT3    = 0.57735026918962576f;
constexpr float ISQRT32   = 0.17677669529663687f;   // 1/sqrt(32)
constexpr float C_TP      = 0.14433756729740645f;   // 1/sqrt(48)
constexpr float CSIM      = 0.11180339887498949f;   // 1/sqrt(80)
constexpr float PREB      = 5.0596442562694074f;    // sqrt(2/2.5)*sqrt(32)
constexpr float PI_OVER_R = 1.2566370614359172f;    // pi/2.5
constexpr float INV_RMAX  = 0.4f;
constexpr float HKSC      = C_TP * ISQRT32;         // folded into hidden vec

__device__ __forceinline__ unsigned fkey(float f) {
  unsigned u = __float_as_uint(f);
  return (u & 0x80000000u) ? ~u : (u | 0x80000000u);
}
__device__ __forceinline__ float funkey(unsigned k) {
  return (k & 0x80000000u) ? __uint_as_float(k ^ 0x80000000u)
                           : __uint_as_float(~k);
}
__device__ __forceinline__ unsigned short f2bf(float f) {
  unsigned u = __float_as_uint(f);
  return (unsigned short)((u + 0x7FFFu + ((u >> 16) & 1u)) >> 16);
}

// w-major repacked column -> original W2 column. n in [0,640).
// n<576: n = w*48+u: w<8,u<32 -> 00 block; w<8,u>=32 -> 110 block;
// w in [8,12),u<32 -> 01 block; else zero. n>=576: 10 block (u*4+w').
__device__ __forceinline__ int origcol(int n) {
  if (n >= 576) return 512 + (n - 576);
  int w = n / 48, u = n % 48;
  if (w < 8) return (u < 32) ? (u * 8 + w) : (256 + (u - 32) * 8 + w);
  return (u < 32) ? (384 + u * 4 + (w - 8)) : -1;
}

// ---- K0: weight prep: transpose W1, repack W2 -> bf16 [640][32] ----
__global__ void __launch_bounds__(256) k_prep(
    const float* __restrict__ w_kb1, const float* __restrict__ w_kb2,
    const float* __restrict__ w_vb1, const float* __restrict__ w_vb2,
    float* __restrict__ W1kt, float* __restrict__ W1vt,
    unsigned short* __restrict__ Wtk, unsigned short* __restrict__ Wtv)
{
  int tid = blockIdx.x * 256 + threadIdx.x;
  if (tid < 2 * 640 * 32) {
    int net = tid / (640 * 32), rem = tid % (640 * 32);
    int n = rem / 32, h = rem % 32;
    const float* w2 = net ? w_vb2 : w_kb2;
    unsigned short* Wt = net ? Wtv : Wtk;
    int oc = origcol(n);
    float v = (oc >= 0) ? w2[h * 576 + oc] : 0.0f;
    Wt[n * 32 + h] = f2bf(v);
  }
  if (tid < 2 * 1024) {
    int net = tid / 1024, rem = tid % 1024;
    int h = rem / 32, n2 = rem % 32;
    const float* w1 = net ? w_vb1 : w_kb1;
    float* W1t = net ? W1vt : W1kt;
    W1t[h * 32 + n2] = w1[n2 * 32 + h];
  }
}

// ---- K1n: per-node query projections folded with w_sim ----
__global__ void __launch_bounds__(256) k_node(
    const float* __restrict__ x, const float* __restrict__ w_q0,
    const float* __restrict__ w_q1, const float* __restrict__ w_sim0,
    const float* __restrict__ w_sim1,
    float* __restrict__ qs0, float* __restrict__ qs1)
{
  int n = blockIdx.x * 256 + threadIdx.x;
  if (n >= NN) return;
  float x0[32], x1f[48];
  const float4* xr = (const float4*)(x + 80 * n);
#pragma unroll
  for (int i = 0; i < 8; ++i) {
    float4 v = xr[i];
    x0[4*i]=v.x; x0[4*i+1]=v.y; x0[4*i+2]=v.z; x0[4*i+3]=v.w;
  }
#pragma unroll
  for (int i = 0; i < 12; ++i) {
    float4 v = xr[8 + i];
    x1f[4*i]=v.x; x1f[4*i+1]=v.y; x1f[4*i+2]=v.z; x1f[4*i+3]=v.w;
  }
  float q0[8];
#pragma unroll
  for (int w = 0; w < 8; ++w) {
    float a = 0.f;
#pragma unroll
    for (int u = 0; u < 32; ++u) a = fmaf(x0[u], w_q0[u * 8 + w], a);
    q0[w] = a * ISQRT32;
  }
  float q1[12];
#pragma unroll
  for (int w = 0; w < 4; ++w)
#pragma unroll
    for (int m = 0; m < 3; ++m) {
      float a = 0.f;
#pragma unroll
      for (int u = 0; u < 16; ++u) a = fmaf(x1f[3*u+m], w_q1[u*4+w], a);
      q1[w * 3 + m] = a * 0.25f;
    }
#pragma unroll
  for (int v = 0; v < 8; ++v) {
    float a = 0.f;
#pragma unroll
    for (int u = 0; u < 8; ++u) a = fmaf(w_sim0[u * 8 + v], q0[u], a);
    qs0[n * 8 + v] = CSIM * a;
  }
#pragma unroll
  for (int v = 0; v < 4; ++v)
#pragma unroll
    for (int m = 0; m < 3; ++m) {
      float a = 0.f;
#pragma unroll
      for (int u = 0; u < 4; ++u) a = fmaf(w_sim1[u*4+v], q1[u*3+m], a);
      qs1[n * 12 + v * 3 + m] = (CSIM * ISQRT3) * a;
    }
}

// ---- K1e: per-edge geometry + bessel + hidden vectors (bf16) + xdYs ----
__global__ void __launch_bounds__(256) k_edge(
    const float* __restrict__ x, const float* __restrict__ pos,
    const int* __restrict__ esrc, const int* __restrict__ edst,
    const float* __restrict__ W1kt, const float* __restrict__ W1vt,
    unsigned short* __restrict__ hko, unsigned short* __restrict__ hvo,
    float* __restrict__ gx, float* __restrict__ geom)
{
  int e = blockIdx.x * 256 + threadIdx.x;
  if (e >= NE) return;
  int s = esrc[e], d = edst[e];
  float vx = pos[3*s]   - pos[3*d];
  float vy = pos[3*s+1] - pos[3*d+1];
  float vz = pos[3*s+2] - pos[3*d+2];
  float r = sqrtf(fmaf(vx, vx, fmaf(vy, vy, vz * vz)) + 1e-24f);
  float inv_r = 1.0f / r;

  float rb[32];
  {
    float sn, cth;
    sincosf(PI_OVER_R * r, &sn, &cth);
    float twoc = 2.0f * cth, pre = PREB * inv_r, snm1 = 0.0f;
#pragma unroll
    for (int n = 0; n < 32; ++n) {
      rb[n] = pre * sn;
      float t = fmaf(twoc, sn, -snm1);
      snm1 = sn; sn = t;
    }
  }
  float Yx = SQRT3f * vx * inv_r, Yy = SQRT3f * vy * inv_r, Yz = SQRT3f * vz * inv_r;
  float tc = 10.0f * (1.0f - r * INV_RMAX);
  float cut = (tc > 0.0f) ? __expf(-1.0f / tc) : 0.0f;
  *(float4*)(geom + 4 * e) = make_float4(Yx, Yy, Yz, cut);

  // x1 of source node -> xdYs
  float x1f[48];
  const float4* xr = (const float4*)(x + 80 * s + 32);
#pragma unroll
  for (int i = 0; i < 12; ++i) {
    float4 v = xr[i];
    x1f[4*i]=v.x; x1f[4*i+1]=v.y; x1f[4*i+2]=v.z; x1f[4*i+3]=v.w;
  }
  float xd[16];
#pragma unroll
  for (int u = 0; u < 16; ++u)
    xd[u] = ISQRT3 * fmaf(x1f[3*u], Yx, fmaf(x1f[3*u+1], Yy, x1f[3*u+2] * Yz));
#pragma unroll
  for (int i = 0; i < 4; ++i)
    *(float4*)(gx + e * 16 + 4 * i) = make_float4(xd[4*i], xd[4*i+1], xd[4*i+2], xd[4*i+3]);

  // hidden vectors: silu((rb@W1)/sqrt32) * HKSC, both nets
#pragma unroll 1
  for (int h = 0; h < 32; ++h) {
    const float* wk = W1kt + h * 32;
    const float* wv = W1vt + h * 32;
    float ak = 0.f, av = 0.f;
#pragma unroll
    for (int n = 0; n < 32; ++n) {
      ak = fmaf(rb[n], wk[n], ak);
      av = fmaf(rb[n], wv[n], av);
    }
    ak *= ISQRT32; av *= ISQRT32;
    float hk_ = ak / (1.0f + __expf(-ak)) * HKSC;
    float hv_ = av / (1.0f + __expf(-av)) * HKSC;
    hko[e * 32 + h] = f2bf(hk_);
    hvo[e * 32 + h] = f2bf(hv_);
  }
}

// ---- K2: MFMA tensor-product kernel. KNET=1: logits; KNET=0: scatter ----
template <int KNET>
__global__ void __launch_bounds__(256) k_tp(
    const unsigned short* __restrict__ hmat, const unsigned short* __restrict__ Wt,
    const float* __restrict__ x, const float* __restrict__ gx,
    const float* __restrict__ geom,
    const int* __restrict__ esrc, const int* __restrict__ edst,
    const float* __restrict__ qs0, const float* __restrict__ qs1,
    const float* __restrict__ exb, const float* __restrict__ den,
    float* __restrict__ logits, unsigned* __restrict__ mkey,
    float* __restrict__ out)
{
  __shared__ float g_lds[4][800];     // 16 edges x 48 feats, stride 50
  __shared__ float tw_lds[4][1056];   // 16 edges x 64 Tw, stride 66
  __shared__ float s01_lds[4][64];
  __shared__ float k0_lds[4][128];

  const int l = threadIdx.x & 63, wv = threadIdx.x >> 6;
  const int tile = blockIdx.x * 4 + wv;
  const int G = l >> 4, c = l & 15;
  const int ebase = tile * 16;

  // stage x0 (cols 0..31) from x[src], xdYs (cols 32..47) from gx
#pragma unroll
  for (int i = 0; i < 2; ++i) {
    int idx = i * 64 + l;             // 0..127 -> edge(0..15) x q(0..7)
    int ee = idx >> 3, q = idx & 7;
    int ss = esrc[ebase + ee];
    float4 v = *(const float4*)(x + 80 * ss + 4 * q);
    float* p = &g_lds[wv][ee * 50 + 4 * q];
    p[0] = v.x; p[1] = v.y; p[2] = v.z; p[3] = v.w;
  }
  {
    int ee = l >> 2, q = l & 3;
    float4 v = *(const float4*)(gx + (ebase + ee) * 16 + 4 * q);
    float* p = &g_lds[wv][ee * 50 + 32 + 4 * q];
    p[0] = v.x; p[1] = v.y; p[2] = v.z; p[3] = v.w;
  }

  // A fragment: hk[e = ebase+c][k = 8G..8G+7]
  short8 a8 = *(const short8*)(hmat + (ebase + c) * 32 + 8 * G);

  float vacc[4][12];
#pragma unroll
  for (int r = 0; r < 4; ++r)
#pragma unroll
    for (int w = 0; w < 12; ++w) vacc[r][w] = 0.0f;

  const f32x4 zero4 = {0.f, 0.f, 0.f, 0.f};
  // w-major tiles: T[e][n=w*48+u], fused epilogue *g
#pragma unroll
  for (int t = 0; t < 36; ++t) {
    short8 b8 = *(const short8*)(Wt + (t * 16 + c) * 32 + 8 * G);
    f32x4 dd = __builtin_amdgcn_mfma_f32_16x16x32_bf16(a8, b8, zero4, 0, 0, 0);
    const int w = t / 3, u0 = (t % 3) * 16;
#pragma unroll
    for (int r = 0; r < 4; ++r)
      vacc[r][w] = fmaf(dd[r], g_lds[wv][(4 * G + r) * 50 + u0 + c], vacc[r][w]);
  }
  // 10-block tiles -> Tw to LDS
#pragma unroll
  for (int t = 36; t < 40; ++t) {
    short8 b8 = *(const short8*)(Wt + (t * 16 + c) * 32 + 8 * G);
    f32x4 dd = __builtin_amdgcn_mfma_f32_16x16x32_bf16(a8, b8, zero4, 0, 0, 0);
#pragma unroll
    for (int r = 0; r < 4; ++r)
      tw_lds[wv][(4 * G + r) * 66 + (t - 36) * 16 + c] = dd[r];
  }

  // butterfly sum over the 16 u-partial lanes (c)
#pragma unroll
  for (int m = 1; m < 16; m <<= 1)
#pragma unroll
    for (int r = 0; r < 4; ++r)
#pragma unroll
      for (int w = 0; w < 12; ++w)
        vacc[r][w] += __shfl_xor(vacc[r][w], m);

  // lane c picks column w==c (static vacc indexing)
  float treg[4] = {0.f, 0.f, 0.f, 0.f};
#pragma unroll
  for (int w = 0; w < 12; ++w)
    if (c == w) {
#pragma unroll
      for (int r = 0; r < 4; ++r) treg[r] = vacc[r][w];
    }

  if (c < 8) {
    if (KNET) {
#pragma unroll
      for (int r = 0; r < 4; ++r)
        k0_lds[wv][(4 * G + r) * 8 + c] = treg[r];
    } else {
#pragma unroll
      for (int r = 0; r < 4; ++r) {
        int eg = ebase + 4 * G + r;
        int sr = esrc[eg];
        float a = sqrtf(fmaxf(exb[eg] / den[sr], 0.f)) * 0.03125f;
        atomicAdd(out + 20 * edst[eg] + c, a * treg[r]);
      }
    }
  } else if (c < 12) {
#pragma unroll
    for (int r = 0; r < 4; ++r)
      s01_lds[wv][(4 * G + r) * 4 + (c - 8)] = treg[r];
  }

  // phase 2: per (edge, w4) lane: out1 = Tw . x1 + s01*Y; then sim / scatter
  const int e2 = l >> 2, w4 = l & 3;
  const int eg = ebase + e2;
  const int s2 = esrc[eg];
  float4 gm = *(const float4*)(geom + 4 * eg);

  float xs[48];
  {
    const float4* xp = (const float4*)(x + 80 * s2 + 32);
#pragma unroll
    for (int i = 0; i < 12; ++i) {
      float4 v = xp[i];
      xs[4*i]=v.x; xs[4*i+1]=v.y; xs[4*i+2]=v.z; xs[4*i+3]=v.w;
    }
  }
  float v1[3] = {0.f, 0.f, 0.f};
#pragma unroll
  for (int u = 0; u < 16; ++u) {
    float tv = tw_lds[wv][e2 * 66 + 4 * u + w4];
    v1[0] = fmaf(tv, xs[3*u],   v1[0]);
    v1[1] = fmaf(tv, xs[3*u+1], v1[1]);
    v1[2] = fmaf(tv, xs[3*u+2], v1[2]);
  }
  float s01v = s01_lds[wv][e2 * 4 + w4];
  v1[0] = fmaf(s01v, gm.x, v1[0]);
  v1[1] = fmaf(s01v, gm.y, v1[1]);
  v1[2] = fmaf(s01v, gm.z, v1[2]);

  if (KNET) {
    float k0a = k0_lds[wv][e2 * 8 + 2 * w4];
    float k0b = k0_lds[wv][e2 * 8 + 2 * w4 + 1];
    const float* q0p = qs0 + s2 * 8 + 2 * w4;
    const float* q1p = qs1 + s2 * 12 + w4 * 3;
    float part = k0a * q0p[0] + k0b * q0p[1]
               + v1[0] * q1p[0] + v1[1] * q1p[1] + v1[2] * q1p[2];
    part += __shfl_xor(part, 1);
    part += __shfl_xor(part, 2);
    if (w4 == 0) {
      float lg = gm.w * part;
      logits[eg] = lg;
      atomicMax(mkey + s2, fkey(lg));
    }
  } else {
    float a = sqrtf(fmaxf(exb[eg] / den[s2], 0.f)) * 0.03125f;
    int dd = edst[eg];
#pragma unroll
    for (int m = 0; m < 3; ++m)
      atomicAdd(out + 20 * dd + 8 + 3 * w4 + m, a * v1[m]);
  }
}

// ---- softmax denominator ----
__global__ void __launch_bounds__(256) k_softmax_den(
    const float* __restrict__ logits, const int* __restrict__ esrc,
    const unsigned* __restrict__ mkey,
    float* __restrict__ exb, float* __restrict__ den)
{
  int e = blockIdx.x * 256 + threadIdx.x;
  if (e >= NE) return;
  int s = esrc[e];
  float m = funkey(mkey[s]);
  float ex = expf(logits[e] - m);
  exb[e] = ex;
  atomicAdd(&den[s], ex);
}

extern "C" void kernel_launch(void* const* d_in, const int* in_sizes, int n_in,
                              void* d_out, int out_size, void* d_ws, size_t ws_size,
                              hipStream_t stream)
{
  const float* x      = (const float*)d_in[0];
  const float* pos    = (const float*)d_in[1];
  const float* w_q0   = (const float*)d_in[2];
  const float* w_q1   = (const float*)d_in[3];
  const float* w_kb1  = (const float*)d_in[4];
  const float* w_kb2  = (const float*)d_in[5];
  const float* w_vb1  = (const float*)d_in[6];
  const float* w_vb2  = (const float*)d_in[7];
  const float* w_sim0 = (const float*)d_in[8];
  const float* w_sim1 = (const float*)d_in[9];
  const int*   eidx   = (const int*)d_in[10];
  const int* esrc = eidx;
  const int* edst = eidx + NE;
  float* out = (float*)d_out;

  // workspace layout (f32 units, all 16B-aligned)
  float* ws     = (float*)d_ws;
  float* gx     = ws;                       // NE*16
  float* geom   = gx + (size_t)NE * 16;     // NE*4
  float* qs0    = geom + (size_t)NE * 4;    // NN*8
  float* qs1    = qs0 + NN * 8;             // NN*12
  float* logits = qs1 + NN * 12;            // NE
  float* exb    = logits + NE;              // NE
  float* W1kt   = exb + NE;                 // 1024
  float* W1vt   = W1kt + 1024;              // 1024
  float* den    = W1vt + 1024;              // NN
  unsigned* mkey = (unsigned*)(den + NN);   // NN
  unsigned short* hk  = (unsigned short*)(mkey + NN);  // NE*32
  unsigned short* hv  = hk + (size_t)NE * 32;          // NE*32
  unsigned short* Wtk = hv + (size_t)NE * 32;          // 640*32
  unsigned short* Wtv = Wtk + 640 * 32;                // 640*32

  hipMemsetAsync(out, 0, (size_t)NN * 20 * sizeof(float), stream);
  hipMemsetAsync(den, 0, (size_t)NN * 2 * sizeof(float), stream); // den+mkey

  k_prep<<<dim3((2 * 640 * 32 + 255) / 256), dim3(256), 0, stream>>>(
      w_kb1, w_kb2, w_vb1, w_vb2, W1kt, W1vt, Wtk, Wtv);
  k_node<<<dim3((NN + 255) / 256), dim3(256), 0, stream>>>(
      x, w_q0, w_q1, w_sim0, w_sim1, qs0, qs1);
  k_edge<<<dim3((NE + 255) / 256), dim3(256), 0, stream>>>(
      x, pos, esrc, edst, W1kt, W1vt, hk, hv, gx, geom);
  k_tp<1><<<dim3(NE / 64), dim3(256), 0, stream>>>(
      hk, Wtk, x, gx, geom, esrc, edst, qs0, qs1, exb, den, logits, mkey, out);
  k_softmax_den<<<dim3((NE + 255) / 256), dim3(256), 0, stream>>>(
      logits, esrc, mkey, exb, den);
  k_tp<0><<<dim3(NE / 64), dim3(256), 0, stream>>>(
      hv, Wtv, x, gx, geom, esrc, edst, qs0, qs1, exb, den, logits, mkey, out);
}

// Round 7
// 184.524 us; speedup vs baseline: 3.3932x; 1.4216x over previous
//
#include <hip/hip_runtime.h>
#include <hip/hip_fp16.h>
#include <math.h>

#define NN 10000
#define NE 160000

typedef _Float16 half8 __attribute__((ext_vector_type(8)));
typedef __attribute__((ext_vector_type(4))) float f32x4;

constexpr float SQRT3f    = 1.7320508075688772f;
constexpr float ISQRT3    = 0.57735026918962576f;
constexpr float ISQRT32   = 0.17677669529663687f;   // 1/sqrt(32)
constexpr float C_TP      = 0.14433756729740645f;   // 1/sqrt(48)
constexpr float CSIM      = 0.11180339887498949f;   // 1/sqrt(80)
constexpr float PREB      = 5.0596442562694074f;    // sqrt(2/2.5)*sqrt(32)
constexpr float PI_OVER_R = 1.2566370614359172f;    // pi/2.5
constexpr float INV_RMAX  = 0.4f;
constexpr float HKSC      = C_TP * ISQRT32;
constexpr float DEN_SCALE = 16777216.0f;            // 2^24
constexpr float DEN_INV   = 1.0f / 16777216.0f;
constexpr float OUT_SCALE = 8388608.0f;             // 2^23 (|out|<=~7 << 256)
constexpr float OUT_INV   = 1.0f / 8388608.0f;

__device__ __forceinline__ unsigned fkey(float f) {
  unsigned u = __float_as_uint(f);
  return (u & 0x80000000u) ? ~u : (u | 0x80000000u);
}
__device__ __forceinline__ float funkey(unsigned k) {
  return (k & 0x80000000u) ? __uint_as_float(k ^ 0x80000000u)
                           : __uint_as_float(~k);
}
__device__ __forceinline__ unsigned short f2h(float f) {
  return __half_as_ushort(__float2half(f));
}

// w-major repacked column -> original W2 column. n in [0,640).
__device__ __forceinline__ int origcol(int n) {
  if (n >= 576) return 512 + (n - 576);
  int w = n / 48, u = n % 48;
  if (w < 8) return (u < 32) ? (u * 8 + w) : (256 + (u - 32) * 8 + w);
  return (u < 32) ? (384 + u * 4 + (w - 8)) : -1;
}

// ---- K0: v-net weight prep (fp16 repack of W2v; fp32 transpose of W1v) ----
__global__ void __launch_bounds__(256) k_prep(
    const float* __restrict__ w_vb1, const float* __restrict__ w_vb2,
    float* __restrict__ W1vt, unsigned short* __restrict__ Wtv)
{
  int tid = blockIdx.x * 256 + threadIdx.x;
  if (tid < 640 * 32) {
    int n = tid / 32, h = tid % 32;
    int oc = origcol(n);
    float v = (oc >= 0) ? w_vb2[h * 576 + oc] : 0.0f;
    Wtv[n * 32 + h] = f2h(v);
  }
  if (tid < 1024) {
    int h = tid / 32, n2 = tid % 32;
    W1vt[h * 32 + n2] = w_vb1[n2 * 32 + h];
  }
}

// ---- K1n: per-node query projections folded with w_sim ----
__global__ void __launch_bounds__(256) k_node(
    const float* __restrict__ x, const float* __restrict__ w_q0,
    const float* __restrict__ w_q1, const float* __restrict__ w_sim0,
    const float* __restrict__ w_sim1,
    float* __restrict__ qs0, float* __restrict__ qs1)
{
  int n = blockIdx.x * 256 + threadIdx.x;
  if (n >= NN) return;
  float x0[32], x1f[48];
  const float4* xr = (const float4*)(x + 80 * n);
#pragma unroll
  for (int i = 0; i < 8; ++i) {
    float4 v = xr[i];
    x0[4*i]=v.x; x0[4*i+1]=v.y; x0[4*i+2]=v.z; x0[4*i+3]=v.w;
  }
#pragma unroll
  for (int i = 0; i < 12; ++i) {
    float4 v = xr[8 + i];
    x1f[4*i]=v.x; x1f[4*i+1]=v.y; x1f[4*i+2]=v.z; x1f[4*i+3]=v.w;
  }
  float q0[8];
#pragma unroll
  for (int w = 0; w < 8; ++w) {
    float a = 0.f;
#pragma unroll
    for (int u = 0; u < 32; ++u) a = fmaf(x0[u], w_q0[u * 8 + w], a);
    q0[w] = a * ISQRT32;
  }
  float q1[12];
#pragma unroll
  for (int w = 0; w < 4; ++w)
#pragma unroll
    for (int m = 0; m < 3; ++m) {
      float a = 0.f;
#pragma unroll
      for (int u = 0; u < 16; ++u) a = fmaf(x1f[3*u+m], w_q1[u*4+w], a);
      q1[w * 3 + m] = a * 0.25f;
    }
#pragma unroll
  for (int v = 0; v < 8; ++v) {
    float a = 0.f;
#pragma unroll
    for (int u = 0; u < 8; ++u) a = fmaf(w_sim0[u * 8 + v], q0[u], a);
    qs0[n * 8 + v] = CSIM * a;
  }
#pragma unroll
  for (int v = 0; v < 4; ++v)
#pragma unroll
    for (int m = 0; m < 3; ++m) {
      float a = 0.f;
#pragma unroll
      for (int u = 0; u < 4; ++u) a = fmaf(w_sim1[u*4+v], q1[u*3+m], a);
      qs1[n * 12 + v * 3 + m] = (CSIM * ISQRT3) * a;
    }
}

// ---- K1e: per-edge geometry + bessel + v-net hidden vectors (fp16) ----
__global__ void __launch_bounds__(256) k_edge(
    const float* __restrict__ pos,
    const int* __restrict__ esrc, const int* __restrict__ edst,
    const float* __restrict__ W1vt,
    unsigned* __restrict__ hvo, float* __restrict__ geom,
    float* __restrict__ rbuf)
{
  int e = blockIdx.x * 256 + threadIdx.x;
  if (e >= NE) return;
  int s = esrc[e], d = edst[e];
  float vx = pos[3*s]   - pos[3*d];
  float vy = pos[3*s+1] - pos[3*d+1];
  float vz = pos[3*s+2] - pos[3*d+2];
  float r = sqrtf(fmaf(vx, vx, fmaf(vy, vy, vz * vz)) + 1e-24f);
  float inv_r = 1.0f / r;

  float rb[32];
  {
    float sn, cth;
    sincosf(PI_OVER_R * r, &sn, &cth);
    float twoc = 2.0f * cth, pre = PREB * inv_r, snm1 = 0.0f;
#pragma unroll
    for (int n = 0; n < 32; ++n) {
      rb[n] = pre * sn;
      float t = fmaf(twoc, sn, -snm1);
      snm1 = sn; sn = t;
    }
  }
  float Yx = SQRT3f * vx * inv_r, Yy = SQRT3f * vy * inv_r, Yz = SQRT3f * vz * inv_r;
  float tc = 10.0f * (1.0f - r * INV_RMAX);
  float cut = (tc > 0.0f) ? __expf(-1.0f / tc) : 0.0f;
  *(float4*)(geom + 4 * e) = make_float4(Yx, Yy, Yz, cut);
  rbuf[e] = r;

#pragma unroll 1
  for (int h = 0; h < 32; h += 2) {
    const float* wv0 = W1vt + h * 32;
    const float* wv1 = W1vt + (h + 1) * 32;
    float av0 = 0.f, av1 = 0.f;
#pragma unroll
    for (int n = 0; n < 32; ++n) {
      float rn = rb[n];
      av0 = fmaf(rn, wv0[n], av0);
      av1 = fmaf(rn, wv1[n], av1);
    }
    av0 *= ISQRT32; av1 *= ISQRT32;
    float hv0 = av0 / (1.0f + __expf(-av0)) * HKSC;
    float hv1 = av1 / (1.0f + __expf(-av1)) * HKSC;
    hvo[e * 16 + (h >> 1)] = (unsigned)f2h(hv0) | ((unsigned)f2h(hv1) << 16);
  }
}

// ---- K2a: per-(node,h) hoisted logit tensors: t14 + F[3] ----
// sim(e) = Sum_h hk_h(r) * ( t14[s,h] + F[s,h,:].Y(e) )
template <int HALF>
__global__ void __launch_bounds__(256) k_nodeF(
    const float* __restrict__ x, const float* __restrict__ w_kb2,
    const float* __restrict__ qs0g, const float* __restrict__ qs1g,
    float* __restrict__ nodeF)
{
  __shared__ float W2f[16 * 577];   // 16 h-rows of this half, +1 pad
  __shared__ float ndl[16][100];    // x0[0:32) x1[32:80) qs0[80:88) qs1[88:100)

  const int tid = threadIdx.x;
  const int nb = blockIdx.x * 16;

#pragma unroll
  for (int i = 0; i < 36; ++i) {
    int idx = i * 256 + tid;                 // 0..9215 = 16*576
    int row = idx / 576, col = idx - row * 576;
    W2f[row * 577 + col] = w_kb2[(HALF * 16 + row) * 576 + col];
  }
  for (int j = tid; j < 1600; j += 256) {
    int nn = j / 100, jj = j - nn * 100;
    int n = nb + nn;                          // 625*16 == NN exactly
    float v;
    if (jj < 80)      v = x[80 * n + jj];
    else if (jj < 88) v = qs0g[8 * n + (jj - 80)];
    else              v = qs1g[12 * n + (jj - 88)];
    ndl[nn][jj] = v;
  }
  __syncthreads();

  const int nn = tid >> 4, hh = tid & 15;
  const float* Wh = W2f + hh * 577;
  const float* nd = ndl[nn];

  // t14 = A (w00 against qs0,x0) + D (w10 against x1.qs1 dots)
  float t14 = 0.f;
#pragma unroll
  for (int a = 0; a < 32; ++a) {
    float tmp = 0.f;
#pragma unroll
    for (int v = 0; v < 8; ++v) tmp = fmaf(Wh[a * 8 + v], nd[80 + v], tmp);
    t14 = fmaf(tmp, nd[a], t14);
  }
#pragma unroll
  for (int a = 0; a < 16; ++a)
#pragma unroll
    for (int v = 0; v < 4; ++v) {
      float dotv = fmaf(nd[32 + 3*a], nd[88 + 3*v],
                   fmaf(nd[32 + 3*a + 1], nd[88 + 3*v + 1],
                        nd[32 + 3*a + 2] * nd[88 + 3*v + 2]));
      t14 = fmaf(Wh[512 + a * 4 + v], dotv, t14);
    }

  // F = ISQRT3 * Sum_a Q[a]*x1[a,:]  (B term)  +  Sum_v R[v]*qs1[v,:] (C term)
  float F0 = 0.f, F1 = 0.f, F2 = 0.f;
#pragma unroll
  for (int a = 0; a < 16; ++a) {
    float q = 0.f;
#pragma unroll
    for (int v = 0; v < 8; ++v) q = fmaf(Wh[256 + a * 8 + v], nd[80 + v], q);
    F0 = fmaf(q, nd[32 + 3*a],     F0);
    F1 = fmaf(q, nd[32 + 3*a + 1], F1);
    F2 = fmaf(q, nd[32 + 3*a + 2], F2);
  }
  F0 *= ISQRT3; F1 *= ISQRT3; F2 *= ISQRT3;
#pragma unroll
  for (int v = 0; v < 4; ++v) {
    float rr = 0.f;
#pragma unroll
    for (int a = 0; a < 32; ++a) rr = fmaf(Wh[384 + a * 4 + v], nd[a], rr);
    F0 = fmaf(rr, nd[88 + 3*v],     F0);
    F1 = fmaf(rr, nd[88 + 3*v + 1], F1);
    F2 = fmaf(rr, nd[88 + 3*v + 2], F2);
  }

  const int n = nb + nn, h = HALF * 16 + hh;
  *(float4*)(nodeF + (size_t)(n * 32 + h) * 4) = make_float4(t14, F0, F1, F2);
}

// ---- K2b: exact fp32 per-edge logits ----
__global__ void __launch_bounds__(256) k_elogit(
    const float* __restrict__ rbuf, const float* __restrict__ geom,
    const int* __restrict__ esrc, const float* __restrict__ w_kb1,
    const float* __restrict__ nodeF,
    float* __restrict__ logits, unsigned* __restrict__ mkey)
{
  __shared__ float W1s[32 * 33];   // [n][h], +1 pad
  const int tid = threadIdx.x;
#pragma unroll
  for (int i = 0; i < 4; ++i) {
    int idx = i * 256 + tid;       // 0..1023
    W1s[(idx >> 5) * 33 + (idx & 31)] = w_kb1[idx];
  }
  __syncthreads();

  const int e = blockIdx.x * 256 + tid;
  if (e >= NE) return;
  const int s = esrc[e];
  const float r = rbuf[e];
  const float4 g4 = *(const float4*)(geom + 4 * e);

  float rb[32];
  {
    float sn, cth;
    sincosf(PI_OVER_R * r, &sn, &cth);
    float twoc = 2.0f * cth, pre = PREB / r, snm1 = 0.0f;
#pragma unroll
    for (int n = 0; n < 32; ++n) {
      rb[n] = pre * sn;
      float t = fmaf(twoc, sn, -snm1);
      snm1 = sn; sn = t;
    }
  }

  const float4* nf = (const float4*)(nodeF + (size_t)s * 128);
  float sim = 0.f;
#pragma unroll 1
  for (int h = 0; h < 32; ++h) {
    float ak = 0.f;
#pragma unroll
    for (int n = 0; n < 32; ++n) ak = fmaf(rb[n], W1s[n * 33 + h], ak);
    ak *= ISQRT32;
    float hk = ak / (1.0f + __expf(-ak)) * HKSC;
    float4 f = nf[h];
    float S = fmaf(f.y, g4.x, fmaf(f.z, g4.y, fmaf(f.w, g4.z, f.x)));
    sim = fmaf(hk, S, sim);
  }
  float lg = g4.w * sim;
  logits[e] = lg;
  atomicMax(mkey + s, fkey(lg));
}

// ---- softmax denominator (int fixed-point, deterministic) ----
__global__ void __launch_bounds__(256) k_den(
    const float* __restrict__ logits, const int* __restrict__ esrc,
    const unsigned* __restrict__ mkey,
    float* __restrict__ exb, int* __restrict__ deni)
{
  int e = blockIdx.x * 256 + threadIdx.x;
  if (e >= NE) return;
  int s = esrc[e];
  float m = funkey(mkey[s]);
  float ex = expf(logits[e] - m);
  exb[e] = ex;
  atomicAdd(&deni[s], __float2int_rn(ex * DEN_SCALE));
}

// ---- K2v: fp16 MFMA v-path tensor-product + int-atomic scatter ----
__global__ void __launch_bounds__(256) k_tpv(
    const unsigned short* __restrict__ hmat, const unsigned short* __restrict__ Wt,
    const float* __restrict__ x, const float* __restrict__ geom,
    const int* __restrict__ esrc, const int* __restrict__ edst,
    const float* __restrict__ exb, const int* __restrict__ deni,
    int* __restrict__ outi)
{
  __shared__ __align__(16) uint4  wlds4[2304];        // 36 tiles, 36864 B
  __shared__ __align__(16) float g_lds[4][16 * 52];   // x0 | xdYs
  __shared__ __align__(16) float x1_lds[4][16 * 52];  // x1 (48 floats)

  const int l = threadIdx.x & 63, wv = threadIdx.x >> 6;
  const int tile = blockIdx.x * 4 + wv;
  const int G = l >> 4, c = l & 15;
  const int ebase = tile * 16;

  const uint4* Wt4 = (const uint4*)Wt;
#pragma unroll
  for (int i = 0; i < 9; ++i) {
    int chunk = i * 256 + threadIdx.x;
    wlds4[chunk] = Wt4[chunk];
  }

#pragma unroll
  for (int i = 0; i < 5; ++i) {
    int idx = i * 64 + l;
    int ee = idx / 20, q = idx - 20 * ee;
    int ss = esrc[ebase + ee];
    float4 v = *(const float4*)(x + 80 * ss + 4 * q);
    if (q < 8)
      *(float4*)(&g_lds[wv][ee * 52 + 4 * q]) = v;
    else
      *(float4*)(&x1_lds[wv][ee * 52 + 4 * q - 32]) = v;
  }
  {
    int ee = l >> 2, ug = l & 3;
    int ss = esrc[ebase + ee];
    float4 gm = *(const float4*)(geom + 4 * (ebase + ee));
    const float* xp = x + 80 * ss + 32 + 12 * ug;
    float4 p0 = *(const float4*)(xp);
    float4 p1 = *(const float4*)(xp + 4);
    float4 p2 = *(const float4*)(xp + 8);
    float4 o;
    o.x = ISQRT3 * fmaf(p0.x, gm.x, fmaf(p0.y, gm.y, p0.z * gm.z));
    o.y = ISQRT3 * fmaf(p0.w, gm.x, fmaf(p1.x, gm.y, p1.y * gm.z));
    o.z = ISQRT3 * fmaf(p1.z, gm.x, fmaf(p1.w, gm.y, p2.x * gm.z));
    o.w = ISQRT3 * fmaf(p2.y, gm.x, fmaf(p2.z, gm.y, p2.w * gm.z));
    *(float4*)(&g_lds[wv][ee * 52 + 32 + 4 * ug]) = o;
  }

  half8 a8 = *(const half8*)(hmat + (ebase + c) * 32 + 8 * G);

  __syncthreads();

  half8 bt[4];
#pragma unroll
  for (int t = 0; t < 4; ++t)
    bt[t] = *(const half8*)(Wt + ((36 + t) * 16 + c) * 32 + 8 * G);

  float vacc[4][12];
#pragma unroll
  for (int r = 0; r < 4; ++r)
#pragma unroll
    for (int w = 0; w < 12; ++w) vacc[r][w] = 0.0f;
  float ot1[4][3];
#pragma unroll
  for (int r = 0; r < 4; ++r) { ot1[r][0]=0.f; ot1[r][1]=0.f; ot1[r][2]=0.f; }

  const f32x4 zero4 = {0.f, 0.f, 0.f, 0.f};
#pragma unroll
  for (int t = 0; t < 36; ++t) {
    union { uint4 u; half8 h; } cvt;
    cvt.u = wlds4[(t * 16 + c) * 4 + G];
    f32x4 dd = __builtin_amdgcn_mfma_f32_16x16x32_f16(a8, cvt.h, zero4, 0, 0, 0);
    const int w = t / 3, u0 = (t % 3) * 16;
#pragma unroll
    for (int r = 0; r < 4; ++r)
      vacc[r][w] = fmaf(dd[r], g_lds[wv][(4 * G + r) * 52 + u0 + c], vacc[r][w]);
  }
#pragma unroll
  for (int t = 0; t < 4; ++t) {
    f32x4 dd = __builtin_amdgcn_mfma_f32_16x16x32_f16(a8, bt[t], zero4, 0, 0, 0);
    const int u = 4 * t + (c >> 2);
#pragma unroll
    for (int r = 0; r < 4; ++r) {
      const float* xp = &x1_lds[wv][(4 * G + r) * 52 + 3 * u];
      ot1[r][0] = fmaf(dd[r], xp[0], ot1[r][0]);
      ot1[r][1] = fmaf(dd[r], xp[1], ot1[r][1]);
      ot1[r][2] = fmaf(dd[r], xp[2], ot1[r][2]);
    }
  }

#pragma unroll
  for (int m = 1; m < 16; m <<= 1)
#pragma unroll
    for (int r = 0; r < 4; ++r)
#pragma unroll
      for (int w = 0; w < 12; ++w)
        vacc[r][w] += __shfl_xor(vacc[r][w], m);
#pragma unroll
  for (int m = 4; m < 16; m <<= 1)
#pragma unroll
    for (int r = 0; r < 4; ++r)
#pragma unroll
      for (int k = 0; k < 3; ++k)
        ot1[r][k] += __shfl_xor(ot1[r][k], m);

  float treg[4] = {0.f, 0.f, 0.f, 0.f};
#pragma unroll
  for (int w = 0; w < 12; ++w)
    if (c == w) {
#pragma unroll
      for (int r = 0; r < 4; ++r) treg[r] = vacc[r][w];
    }

  int sr[4]; float4 g4[4];
#pragma unroll
  for (int r = 0; r < 4; ++r) {
    sr[r] = esrc[ebase + 4 * G + r];
    g4[r] = *(const float4*)(geom + 4 * (ebase + 4 * G + r));
  }

  float a_[4]; int dst[4];
#pragma unroll
  for (int r = 0; r < 4; ++r) {
    int eg = ebase + 4 * G + r;
    dst[r] = edst[eg];
    float denf = (float)deni[sr[r]] * DEN_INV;
    a_[r] = sqrtf(fmaxf(exb[eg] / denf, 0.f)) * 0.03125f;
  }
  float s01w[4];
#pragma unroll
  for (int r = 0; r < 4; ++r) s01w[r] = __shfl_xor(treg[r], 8);
  if (c < 8) {
#pragma unroll
    for (int r = 0; r < 4; ++r)
      atomicAdd(outi + 20 * dst[r] + c,
                __float2int_rn(a_[r] * treg[r] * OUT_SCALE));
  }
  if (c < 4) {
#pragma unroll
    for (int r = 0; r < 4; ++r) {
      float vx_ = fmaf(s01w[r], g4[r].x, ot1[r][0]);
      float vy_ = fmaf(s01w[r], g4[r].y, ot1[r][1]);
      float vz_ = fmaf(s01w[r], g4[r].z, ot1[r][2]);
      atomicAdd(outi + 20 * dst[r] + 8 + 3 * c + 0,
                __float2int_rn(a_[r] * vx_ * OUT_SCALE));
      atomicAdd(outi + 20 * dst[r] + 8 + 3 * c + 1,
                __float2int_rn(a_[r] * vy_ * OUT_SCALE));
      atomicAdd(outi + 20 * dst[r] + 8 + 3 * c + 2,
                __float2int_rn(a_[r] * vz_ * OUT_SCALE));
    }
  }
}

// ---- final int -> float conversion ----
__global__ void __launch_bounds__(256) k_out(
    const int* __restrict__ outi, float* __restrict__ out)
{
  int i = blockIdx.x * 256 + threadIdx.x;
  if (i < NN * 20) out[i] = (float)outi[i] * OUT_INV;
}

extern "C" void kernel_launch(void* const* d_in, const int* in_sizes, int n_in,
                              void* d_out, int out_size, void* d_ws, size_t ws_size,
                              hipStream_t stream)
{
  const float* x      = (const float*)d_in[0];
  const float* pos    = (const float*)d_in[1];
  const float* w_q0   = (const float*)d_in[2];
  const float* w_q1   = (const float*)d_in[3];
  const float* w_kb1  = (const float*)d_in[4];
  const float* w_kb2  = (const float*)d_in[5];
  const float* w_vb1  = (const float*)d_in[6];
  const float* w_vb2  = (const float*)d_in[7];
  const float* w_sim0 = (const float*)d_in[8];
  const float* w_sim1 = (const float*)d_in[9];
  const int*   eidx   = (const int*)d_in[10];
  const int* esrc = eidx;
  const int* edst = eidx + NE;
  float* out = (float*)d_out;

  float* ws      = (float*)d_ws;
  float* geom    = ws;                         // NE*4
  float* rbuf    = geom + (size_t)NE * 4;      // NE
  float* qs0     = rbuf + NE;                  // NN*8
  float* qs1     = qs0 + NN * 8;               // NN*12
  float* logits  = qs1 + NN * 12;              // NE
  float* exb     = logits + NE;                // NE
  float* W1vt    = exb + NE;                   // 1024
  float* nodeF   = W1vt + 1024;                // NN*128
  int*   deni    = (int*)(nodeF + (size_t)NN * 128); // NN
  unsigned* mkey = (unsigned*)(deni + NN);     // NN
  int*   outi    = (int*)(mkey + NN);          // NN*20
  unsigned short* hv  = (unsigned short*)(outi + NN * 20); // NE*32
  unsigned short* Wtv = hv + (size_t)NE * 32;              // 640*32

  // zero deni + mkey + outi (contiguous, 22*NN ints)
  hipMemsetAsync(deni, 0, (size_t)(NN * 22) * sizeof(int), stream);

  const int eb = (NE + 255) / 256;   // 625
  k_prep<<<dim3((640 * 32 + 255) / 256), dim3(256), 0, stream>>>(
      w_vb1, w_vb2, W1vt, Wtv);
  k_node<<<dim3((NN + 255) / 256), dim3(256), 0, stream>>>(
      x, w_q0, w_q1, w_sim0, w_sim1, qs0, qs1);
  k_edge<<<dim3(eb), dim3(256), 0, stream>>>(
      pos, esrc, edst, W1vt, (unsigned*)hv, geom, rbuf);
  k_nodeF<0><<<dim3(NN / 16), dim3(256), 0, stream>>>(
      x, w_kb2, qs0, qs1, nodeF);
  k_nodeF<1><<<dim3(NN / 16), dim3(256), 0, stream>>>(
      x, w_kb2, qs0, qs1, nodeF);
  k_elogit<<<dim3(eb), dim3(256), 0, stream>>>(
      rbuf, geom, esrc, w_kb1, nodeF, logits, mkey);
  k_den<<<dim3(eb), dim3(256), 0, stream>>>(logits, esrc, mkey, exb, deni);
  k_tpv<<<dim3(NE / 64), dim3(256), 0, stream>>>(
      hv, Wtv, x, geom, esrc, edst, exb, deni, outi);
  k_out<<<dim3((NN * 20 + 255) / 256), dim3(256), 0, stream>>>(outi, out);
}